// Round 9
// baseline (270.640 us; speedup 1.0000x reference)
//
#include <hip/hip_runtime.h>
#include <hip/hip_bf16.h>
#include <math.h>

#define DIM 64
#define GNUM 256
#define CNUM 10

// bf16x2 pack (RNE) — final layer's streamed output only.
__device__ __forceinline__ unsigned bfpack(float a, float b) {
    unsigned ua = __builtin_bit_cast(unsigned, a);
    unsigned ub = __builtin_bit_cast(unsigned, b);
    ua += 0x7fffu + ((ua >> 16) & 1u);
    ub += 0x7fffu + ((ub >> 16) & 1u);
    return (ua >> 16) | (ub & 0xffff0000u);
}
__device__ __forceinline__ float bfs(unsigned short u) { return __builtin_bit_cast(float, (unsigned)u << 16); }

// ---------------- fp8 (OCP e4m3) pack/unpack via gfx950 HW cvt ----------------
// h rows stored fp8 -> 64B/row. R17: the ONLY random access per edge is this
// one 64B row fetch; as[src] is recomputed from the fetched row (dot with
// a_src held in registers), eliminating the per-edge as_ gather + the whole
// LDS edge-weight phase (transaction-count theory from R12/R15/R16 nulls).
typedef float floatx2 __attribute__((ext_vector_type(2)));
__device__ __forceinline__ unsigned fp8x4_enc(float a, float b, float c, float d) {
    int w = __builtin_amdgcn_cvt_pk_fp8_f32(a, b, 0, false);    // bytes 0,1 (RNE, sat)
    w = __builtin_amdgcn_cvt_pk_fp8_f32(c, d, w, true);         // bytes 2,3
    return (unsigned)w;
}
__device__ __forceinline__ void fp8dec8(uint2 h, float* f) {
    floatx2 p0 = __builtin_amdgcn_cvt_pk_f32_fp8((int)h.x, false);
    floatx2 p1 = __builtin_amdgcn_cvt_pk_f32_fp8((int)h.x, true);
    floatx2 p2 = __builtin_amdgcn_cvt_pk_f32_fp8((int)h.y, false);
    floatx2 p3 = __builtin_amdgcn_cvt_pk_f32_fp8((int)h.y, true);
    f[0] = p0[0]; f[1] = p0[1]; f[2] = p1[0]; f[3] = p1[1];
    f[4] = p2[0]; f[5] = p2[1]; f[6] = p3[0]; f[7] = p3[1];
}

// ---------------- CSR build ----------------
__global__ void deg_rank_kernel(const int* __restrict__ ei, int E, int N,
                                int* __restrict__ deg, int* __restrict__ rank) {
    int i = blockIdx.x * blockDim.x + threadIdx.x;
    int EP = E + N;
    if (i >= EP) return;
    int d = (i < E) ? ei[E + i] : (i - E);   // row 1 of edge_index = dst; self loops appended
    rank[i] = atomicAdd(&deg[d], 1);
}

// scan_blocks + graph_bounds, role-split by blockIdx.
__global__ __launch_bounds__(256) void scan_misc(const int* __restrict__ deg, int* __restrict__ part, int n, int nb,
                                                 const int* __restrict__ batch, int N,
                                                 int* __restrict__ gstart) {
    int bid = blockIdx.x;
    if (bid < nb) {
        __shared__ int ws[4];
        int i = bid * 256 + threadIdx.x;
        int v = (i < n) ? deg[i] : 0;
        #pragma unroll
        for (int d = 32; d >= 1; d >>= 1) v += __shfl_xor(v, d);
        if ((threadIdx.x & 63) == 0) ws[threadIdx.x >> 6] = v;
        __syncthreads();
        if (threadIdx.x == 0) part[bid] = ws[0] + ws[1] + ws[2] + ws[3];
    } else {
        for (int g = threadIdx.x; g <= GNUM; g += 256) {
            int lo = 0, hi = N;
            while (lo < hi) { int mid = (lo + hi) >> 1; if (batch[mid] < g) lo = mid + 1; else hi = mid; }
            gstart[g] = lo;
        }
    }
}

// scan_down with the top-level scan fused (nb <= 256 for N <= 65536).
__global__ __launch_bounds__(256) void scan_down(const int* __restrict__ deg, const int* __restrict__ part,
                                                 int* __restrict__ offs, int n) {
    __shared__ int ws[4];
    __shared__ int base_s;
    int tid = threadIdx.x, lane = tid & 63, wid = tid >> 6;
    int pv = (tid < (int)blockIdx.x) ? part[tid] : 0;
    #pragma unroll
    for (int d = 32; d >= 1; d >>= 1) pv += __shfl_xor(pv, d);
    if (lane == 0) ws[wid] = pv;
    __syncthreads();
    if (tid == 0) base_s = ws[0] + ws[1] + ws[2] + ws[3];
    __syncthreads();
    int i = blockIdx.x * 256 + tid;
    int v = (i < n) ? deg[i] : 0;
    int x = v;
    #pragma unroll
    for (int d = 1; d < 64; d <<= 1) { int t = __shfl_up(x, d); if (lane >= d) x += t; }
    if (lane == 63) ws[wid] = x;
    __syncthreads();
    int add = base_s;
    for (int w = 0; w < wid; ++w) add += ws[w];
    if (i < n) offs[i] = add + x - v;
    if (i == n - 1) offs[n] = add + x;
}

// ---------------- fused-alpha fp8 gather (R17) ----------------
// 8-lane group per node. Per edge: one uint2 fetch (64B/row across the
// group), decode, dot with a_src (registers) -> 3-shfl group reduce ->
// w = exp(leaky(as+ad)) -> weighted accumulate. No precomputed weights.
__device__ __forceinline__ void gat_gather_fa(const unsigned* __restrict__ hb,
                                              const int* __restrict__ lsrc,
                                              int ls, int deg, int fg,
                                              const float* __restrict__ av, float adi,
                                              float& a0, float& a1, float& a2, float& a3,
                                              float& a4, float& a5, float& a6, float& a7,
                                              float& sw) {
    for (int eb = 0; eb < deg; eb += 4) {
        int t = ls + eb;
        int s0 = lsrc[t], s1 = lsrc[t + 1], s2 = lsrc[t + 2], s3 = lsrc[t + 3];
        const uint2 h0 = *(const uint2*)(hb + ((size_t)s0 << 4) + (fg << 1));
        const uint2 h1 = *(const uint2*)(hb + ((size_t)s1 << 4) + (fg << 1));
        const uint2 h2 = *(const uint2*)(hb + ((size_t)s2 << 4) + (fg << 1));
        const uint2 h3 = *(const uint2*)(hb + ((size_t)s3 << 4) + (fg << 1));
        float f0[8], f1[8], f2[8], f3[8];
        fp8dec8(h0, f0); fp8dec8(h1, f1); fp8dec8(h2, f2); fp8dec8(h3, f3);
        float d0 = 0.f, d1 = 0.f, d2 = 0.f, d3 = 0.f;
        #pragma unroll
        for (int j = 0; j < 8; ++j) {
            d0 += f0[j] * av[j]; d1 += f1[j] * av[j];
            d2 += f2[j] * av[j]; d3 += f3[j] * av[j];
        }
        #pragma unroll
        for (int d = 1; d <= 4; d <<= 1) {
            d0 += __shfl_xor(d0, d); d1 += __shfl_xor(d1, d);
            d2 += __shfl_xor(d2, d); d3 += __shfl_xor(d3, d);
        }
        float e0 = d0 + adi, e1 = d1 + adi, e2 = d2 + adi, e3 = d3 + adi;
        e0 = (e0 > 0.f) ? e0 : 0.2f * e0;
        e1 = (e1 > 0.f) ? e1 : 0.2f * e1;
        e2 = (e2 > 0.f) ? e2 : 0.2f * e2;
        e3 = (e3 > 0.f) ? e3 : 0.2f * e3;
        int rem = deg - eb;
        float w0 = expf(e0);
        float w1 = (rem > 1) ? expf(e1) : 0.f;
        float w2 = (rem > 2) ? expf(e2) : 0.f;
        float w3 = (rem > 3) ? expf(e3) : 0.f;
        sw += (w0 + w1) + (w2 + w3);
        a0 += w0 * f0[0] + w1 * f1[0] + w2 * f2[0] + w3 * f3[0];
        a1 += w0 * f0[1] + w1 * f1[1] + w2 * f2[1] + w3 * f3[1];
        a2 += w0 * f0[2] + w1 * f1[2] + w2 * f2[2] + w3 * f3[2];
        a3 += w0 * f0[3] + w1 * f1[3] + w2 * f2[3] + w3 * f3[3];
        a4 += w0 * f0[4] + w1 * f1[4] + w2 * f2[4] + w3 * f3[4];
        a5 += w0 * f0[5] + w1 * f1[5] + w2 * f2[5] + w3 * f3[5];
        a6 += w0 * f0[6] + w1 * f1[6] + w2 * f2[6] + w3 * f3[6];
        a7 += w0 * f0[7] + w1 * f1[7] + w2 * f2[7] + w3 * f3[7];
    }
}

// ---------------- 512-thread 64x64 mm pieces ----------------
#define XSTR 68
// hbn rows fp8 (16 words). Epilogue computes only ad (dst dot) — as is
// recomputed on the fly by the next agg from the stored rows.
__device__ __forceinline__ void mm_core_512(const float* __restrict__ xT, const float* __restrict__ Ws,
                                            const float* __restrict__ adv,
                                            unsigned* __restrict__ hbn, float* __restrict__ adn,
                                            int base, int N) {
    int tid = threadIdx.x;
    int tx = tid & 15, ty = tid >> 4;          // ty 0..31
    int c0 = tx << 2, r0 = ty << 1;
    float acc[2][4] = {{0.f}};
    #pragma unroll 8
    for (int k = 0; k < DIM; ++k) {
        float2 xv = *(const float2*)(xT + k * XSTR + r0);
        float4 wv = *(const float4*)(Ws + k * DIM + c0);
        acc[0][0] += xv.x * wv.x; acc[0][1] += xv.x * wv.y; acc[0][2] += xv.x * wv.z; acc[0][3] += xv.x * wv.w;
        acc[1][0] += xv.y * wv.x; acc[1][1] += xv.y * wv.y; acc[1][2] += xv.y * wv.z; acc[1][3] += xv.y * wv.w;
    }
    float4 dv = *(const float4*)(adv + c0);
    #pragma unroll
    for (int ri = 0; ri < 2; ++ri) {
        int grow = base + r0 + ri;
        float s2 = acc[ri][0] * dv.x + acc[ri][1] * dv.y + acc[ri][2] * dv.z + acc[ri][3] * dv.w;
        #pragma unroll
        for (int d = 1; d <= 8; d <<= 1) s2 += __shfl_xor(s2, d);
        if (grow < N) {
            hbn[((size_t)grow << 4) + tx] = fp8x4_enc(acc[ri][0], acc[ri][1], acc[ri][2], acc[ri][3]);
            if (tx == 0) adn[grow] = s2;
        }
    }
}

// layer-1 mm (f32 input, 512 threads) + atomic-free CSR scatter (src only).
__global__ __launch_bounds__(512) void mm_fill(const float* __restrict__ in, const float* __restrict__ W,
                                               const float* __restrict__ adv,
                                               unsigned* __restrict__ hb, float* __restrict__ ad_,
                                               int N, int nbt,
                                               const int* __restrict__ ei, const int* __restrict__ rank, int E,
                                               const int* __restrict__ offs, int* __restrict__ csr) {
    int bid = blockIdx.x;
    if (bid < nbt) {
        __shared__ float Ws[DIM * DIM];
        __shared__ float xT[XSTR * DIM];
        int tid = threadIdx.x;
        int base = bid * 64;

        const float4* W4 = (const float4*)W;
        float4* Ws4 = (float4*)Ws;
        Ws4[tid] = W4[tid];
        Ws4[tid + 512] = W4[tid + 512];

        {
            int row = tid >> 3;
            int kb = (tid & 7) << 3;
            int grow = base + row;
            int crow = grow < N ? grow : N - 1;
            const float4* xr = (const float4*)(in + ((size_t)crow << 6) + kb);
            float4 v0 = xr[0], v1 = xr[1];
            xT[(kb + 0) * XSTR + row] = v0.x;  xT[(kb + 1) * XSTR + row] = v0.y;
            xT[(kb + 2) * XSTR + row] = v0.z;  xT[(kb + 3) * XSTR + row] = v0.w;
            xT[(kb + 4) * XSTR + row] = v1.x;  xT[(kb + 5) * XSTR + row] = v1.y;
            xT[(kb + 6) * XSTR + row] = v1.z;  xT[(kb + 7) * XSTR + row] = v1.w;
        }
        __syncthreads();
        mm_core_512(xT, Ws, adv, hb, ad_, base, N);
    } else {
        int i = (bid - nbt) * 512 + threadIdx.x;
        int EP = E + N;
        if (i >= EP) return;
        int s, d;
        if (i < E) { s = ei[i]; d = ei[E + i]; } else { s = i - E; d = i - E; }
        csr[offs[d] + rank[i]] = s;
    }
}

// ---------------- fused agg(layer k) + mm(layer k+1), 512 threads ----------------
#define FUS_NPB 64
#define FUS_CAP 5120
__global__ __launch_bounds__(512) void agg_mm(const unsigned* __restrict__ hbp,
                                              const int* __restrict__ csr,
                                              const float* __restrict__ adp,
                                              const int* __restrict__ offs,
                                              const float* __restrict__ asv,   // a_src of layer k
                                              const float* __restrict__ bias,
                                              const float* __restrict__ W,     // W of layer k+1
                                              const float* __restrict__ adv,   // a_dst of layer k+1
                                              unsigned* __restrict__ hbn,
                                              float* __restrict__ adn, int N) {
    __shared__ int soffs[FUS_NPB + 1];
    __shared__ float adl[FUS_NPB];
    __shared__ __attribute__((aligned(16))) int lsrc[FUS_CAP + 4];  // 20KB; reused as Ws (16KB)
    __shared__ float xT[XSTR * DIM];                                // 17.4 KB
    float* Ws = (float*)lsrc;

    int tid = threadIdx.x;
    int base = blockIdx.x * FUS_NPB;
    if (tid <= FUS_NPB) {
        int n = base + tid;
        soffs[tid] = offs[n < N ? n : N];
    }
    if (tid < FUS_NPB) {
        int n = base + tid;
        adl[tid] = (n < N) ? adp[n] : 0.f;
    }
    __syncthreads();
    int estart = soffs[0];
    int nE = soffs[FUS_NPB] - estart;
    bool inLds = (nE <= FUS_CAP);
    if (inLds) {
        for (int i = tid; i < nE; i += 512) lsrc[i] = csr[estart + i];
        if (tid < 4) lsrc[nE + tid] = 0;
    }
    __syncthreads();

    int li = tid >> 3, fg = tid & 7;           // one 8-lane group per node
    int node = base + li;
    int ls = soffs[li] - estart;
    int deg = soffs[li + 1] - soffs[li];
    float adi = adl[li];

    float av[8];
    *(float4*)&av[0] = *(const float4*)(asv + (fg << 3));
    *(float4*)&av[4] = *(const float4*)(asv + (fg << 3) + 4);

    float a0 = 0.f, a1 = 0.f, a2 = 0.f, a3 = 0.f;
    float a4 = 0.f, a5 = 0.f, a6 = 0.f, a7 = 0.f, sw = 0.f;
    if (inLds) {
        gat_gather_fa(hbp, lsrc, ls, deg, fg, av, adi, a0, a1, a2, a3, a4, a5, a6, a7, sw);
    } else {
        // cold fallback: srcs from global (clamped), same math
        for (int eb = 0; eb < deg; eb += 4) {
            int t = estart + ls + eb;
            int sv[4];
            #pragma unroll
            for (int k = 0; k < 4; ++k) {
                int s = (eb + k < deg) ? csr[t + k] : 0;
                sv[k] = s < 0 ? 0 : (s >= N ? N - 1 : s);
            }
            float f0[8], f1[8], f2[8], f3[8];
            fp8dec8(*(const uint2*)(hbp + ((size_t)sv[0] << 4) + (fg << 1)), f0);
            fp8dec8(*(const uint2*)(hbp + ((size_t)sv[1] << 4) + (fg << 1)), f1);
            fp8dec8(*(const uint2*)(hbp + ((size_t)sv[2] << 4) + (fg << 1)), f2);
            fp8dec8(*(const uint2*)(hbp + ((size_t)sv[3] << 4) + (fg << 1)), f3);
            float d0 = 0.f, d1 = 0.f, d2 = 0.f, d3 = 0.f;
            #pragma unroll
            for (int j = 0; j < 8; ++j) {
                d0 += f0[j] * av[j]; d1 += f1[j] * av[j];
                d2 += f2[j] * av[j]; d3 += f3[j] * av[j];
            }
            #pragma unroll
            for (int d = 1; d <= 4; d <<= 1) {
                d0 += __shfl_xor(d0, d); d1 += __shfl_xor(d1, d);
                d2 += __shfl_xor(d2, d); d3 += __shfl_xor(d3, d);
            }
            float e0 = d0 + adi, e1 = d1 + adi, e2 = d2 + adi, e3 = d3 + adi;
            e0 = (e0 > 0.f) ? e0 : 0.2f * e0;
            e1 = (e1 > 0.f) ? e1 : 0.2f * e1;
            e2 = (e2 > 0.f) ? e2 : 0.2f * e2;
            e3 = (e3 > 0.f) ? e3 : 0.2f * e3;
            int rem = deg - eb;
            float w0 = expf(e0);
            float w1 = (rem > 1) ? expf(e1) : 0.f;
            float w2 = (rem > 2) ? expf(e2) : 0.f;
            float w3 = (rem > 3) ? expf(e3) : 0.f;
            sw += (w0 + w1) + (w2 + w3);
            a0 += w0 * f0[0] + w1 * f1[0] + w2 * f2[0] + w3 * f3[0];
            a1 += w0 * f0[1] + w1 * f1[1] + w2 * f2[1] + w3 * f3[1];
            a2 += w0 * f0[2] + w1 * f1[2] + w2 * f2[2] + w3 * f3[2];
            a3 += w0 * f0[3] + w1 * f1[3] + w2 * f2[3] + w3 * f3[3];
            a4 += w0 * f0[4] + w1 * f1[4] + w2 * f2[4] + w3 * f3[4];
            a5 += w0 * f0[5] + w1 * f1[5] + w2 * f2[5] + w3 * f3[5];
            a6 += w0 * f0[6] + w1 * f1[6] + w2 * f2[6] + w3 * f3[6];
            a7 += w0 * f0[7] + w1 * f1[7] + w2 * f2[7] + w3 * f3[7];
        }
    }

    float inv = 1.f / (sw + 1e-16f);
    const float4 b0 = *(const float4*)(bias + (fg << 3));
    const float4 b1 = *(const float4*)(bias + (fg << 3) + 4);
    float o0 = a0 * inv + b0.x, o1 = a1 * inv + b0.y, o2 = a2 * inv + b0.z, o3 = a3 * inv + b0.w;
    float o4 = a4 * inv + b1.x, o5 = a5 * inv + b1.y, o6 = a6 * inv + b1.z, o7 = a7 * inv + b1.w;
    float n2 = o0 * o0 + o1 * o1 + o2 * o2 + o3 * o3 + o4 * o4 + o5 * o5 + o6 * o6 + o7 * o7;
    #pragma unroll
    for (int d = 1; d <= 4; d <<= 1) n2 += __shfl_xor(n2, d);   // across the 8 fg lanes
    float innrm = 1.f / fmaxf(sqrtf(n2), 1e-12f);
    if (node >= N) innrm = 0.f;                // keep xT clean for pad rows
    int kb = fg << 3;
    xT[(kb + 0) * XSTR + li] = fmaxf(o0 * innrm, 0.f);
    xT[(kb + 1) * XSTR + li] = fmaxf(o1 * innrm, 0.f);
    xT[(kb + 2) * XSTR + li] = fmaxf(o2 * innrm, 0.f);
    xT[(kb + 3) * XSTR + li] = fmaxf(o3 * innrm, 0.f);
    xT[(kb + 4) * XSTR + li] = fmaxf(o4 * innrm, 0.f);
    xT[(kb + 5) * XSTR + li] = fmaxf(o5 * innrm, 0.f);
    xT[(kb + 6) * XSTR + li] = fmaxf(o6 * innrm, 0.f);
    xT[(kb + 7) * XSTR + li] = fmaxf(o7 * innrm, 0.f);
    __syncthreads();                            // agg done; lsrc region free

    const float4* W4 = (const float4*)W;
    float4* Ws4 = (float4*)Ws;
    Ws4[tid] = W4[tid];
    Ws4[tid + 512] = W4[tid + 512];
    __syncthreads();
    mm_core_512(xT, Ws, adv, hbn, adn, base, N);
}

// ---------------- final-layer agg (512 threads, bf16 rows out) ----------------
#define AGG_NPB 64
#define AGG_CAP 5120
__global__ __launch_bounds__(512) void gat_agg(const unsigned* __restrict__ hb,
                                               const int* __restrict__ csr,
                                               const float* __restrict__ adp,
                                               const int* __restrict__ offs,
                                               const float* __restrict__ asv,
                                               const float* __restrict__ bias,
                                               unsigned* __restrict__ outb, int N) {
    __shared__ int soffs[AGG_NPB + 1];
    __shared__ float adl[AGG_NPB];
    __shared__ __attribute__((aligned(16))) int lsrc[AGG_CAP + 4];
    int tid = threadIdx.x;
    int base = blockIdx.x * AGG_NPB;
    if (tid <= AGG_NPB) {
        int n = base + tid;
        soffs[tid] = offs[n < N ? n : N];
    }
    if (tid < AGG_NPB) {
        int n = base + tid;
        adl[tid] = (n < N) ? adp[n] : 0.f;
    }
    __syncthreads();
    int estart = soffs[0];
    int nE = soffs[AGG_NPB] - estart;
    bool inLds = (nE <= AGG_CAP);
    if (inLds) {
        for (int i = tid; i < nE; i += 512) lsrc[i] = csr[estart + i];
        if (tid < 4) lsrc[nE + tid] = 0;
    }
    __syncthreads();

    int li = tid >> 3, fg = tid & 7;
    int node = base + li;
    int ls = soffs[li] - estart;
    int deg = soffs[li + 1] - soffs[li];
    float adi = adl[li];

    float av[8];
    *(float4*)&av[0] = *(const float4*)(asv + (fg << 3));
    *(float4*)&av[4] = *(const float4*)(asv + (fg << 3) + 4);

    float a0 = 0.f, a1 = 0.f, a2 = 0.f, a3 = 0.f;
    float a4 = 0.f, a5 = 0.f, a6 = 0.f, a7 = 0.f, sw = 0.f;
    if (inLds) {
        gat_gather_fa(hb, lsrc, ls, deg, fg, av, adi, a0, a1, a2, a3, a4, a5, a6, a7, sw);
    } else {
        for (int eb = 0; eb < deg; eb += 4) {
            int t = estart + ls + eb;
            int sv[4];
            #pragma unroll
            for (int k = 0; k < 4; ++k) {
                int s = (eb + k < deg) ? csr[t + k] : 0;
                sv[k] = s < 0 ? 0 : (s >= N ? N - 1 : s);
            }
            float f0[8], f1[8], f2[8], f3[8];
            fp8dec8(*(const uint2*)(hb + ((size_t)sv[0] << 4) + (fg << 1)), f0);
            fp8dec8(*(const uint2*)(hb + ((size_t)sv[1] << 4) + (fg << 1)), f1);
            fp8dec8(*(const uint2*)(hb + ((size_t)sv[2] << 4) + (fg << 1)), f2);
            fp8dec8(*(const uint2*)(hb + ((size_t)sv[3] << 4) + (fg << 1)), f3);
            float d0 = 0.f, d1 = 0.f, d2 = 0.f, d3 = 0.f;
            #pragma unroll
            for (int j = 0; j < 8; ++j) {
                d0 += f0[j] * av[j]; d1 += f1[j] * av[j];
                d2 += f2[j] * av[j]; d3 += f3[j] * av[j];
            }
            #pragma unroll
            for (int d = 1; d <= 4; d <<= 1) {
                d0 += __shfl_xor(d0, d); d1 += __shfl_xor(d1, d);
                d2 += __shfl_xor(d2, d); d3 += __shfl_xor(d3, d);
            }
            float e0 = d0 + adi, e1 = d1 + adi, e2 = d2 + adi, e3 = d3 + adi;
            e0 = (e0 > 0.f) ? e0 : 0.2f * e0;
            e1 = (e1 > 0.f) ? e1 : 0.2f * e1;
            e2 = (e2 > 0.f) ? e2 : 0.2f * e2;
            e3 = (e3 > 0.f) ? e3 : 0.2f * e3;
            int rem = deg - eb;
            float w0 = expf(e0);
            float w1 = (rem > 1) ? expf(e1) : 0.f;
            float w2 = (rem > 2) ? expf(e2) : 0.f;
            float w3 = (rem > 3) ? expf(e3) : 0.f;
            sw += (w0 + w1) + (w2 + w3);
            a0 += w0 * f0[0] + w1 * f1[0] + w2 * f2[0] + w3 * f3[0];
            a1 += w0 * f0[1] + w1 * f1[1] + w2 * f2[1] + w3 * f3[1];
            a2 += w0 * f0[2] + w1 * f1[2] + w2 * f2[2] + w3 * f3[2];
            a3 += w0 * f0[3] + w1 * f1[3] + w2 * f2[3] + w3 * f3[3];
            a4 += w0 * f0[4] + w1 * f1[4] + w2 * f2[4] + w3 * f3[4];
            a5 += w0 * f0[5] + w1 * f1[5] + w2 * f2[5] + w3 * f3[5];
            a6 += w0 * f0[6] + w1 * f1[6] + w2 * f2[6] + w3 * f3[6];
            a7 += w0 * f0[7] + w1 * f1[7] + w2 * f2[7] + w3 * f3[7];
        }
    }

    float inv = 1.f / (sw + 1e-16f);
    const float4 b0 = *(const float4*)(bias + (fg << 3));
    const float4 b1 = *(const float4*)(bias + (fg << 3) + 4);
    float o0 = a0 * inv + b0.x, o1 = a1 * inv + b0.y, o2 = a2 * inv + b0.z, o3 = a3 * inv + b0.w;
    float o4 = a4 * inv + b1.x, o5 = a5 * inv + b1.y, o6 = a6 * inv + b1.z, o7 = a7 * inv + b1.w;
    float n2 = o0 * o0 + o1 * o1 + o2 * o2 + o3 * o3 + o4 * o4 + o5 * o5 + o6 * o6 + o7 * o7;
    #pragma unroll
    for (int d = 1; d <= 4; d <<= 1) n2 += __shfl_xor(n2, d);
    float innrm = 1.f / fmaxf(sqrtf(n2), 1e-12f);
    if (node < N) {
        uint4 o;
        o.x = bfpack(fmaxf(o0 * innrm, 0.f), fmaxf(o1 * innrm, 0.f));
        o.y = bfpack(fmaxf(o2 * innrm, 0.f), fmaxf(o3 * innrm, 0.f));
        o.z = bfpack(fmaxf(o4 * innrm, 0.f), fmaxf(o5 * innrm, 0.f));
        o.w = bfpack(fmaxf(o6 * innrm, 0.f), fmaxf(o7 * innrm, 0.f));
        *(uint4*)(outb + ((size_t)node << 5) + (fg << 2)) = o;
    }
}

// ---------------- fused global_add_pool + MLP + log_softmax ----------------
__global__ __launch_bounds__(256) void pool_mlp(const unsigned short* __restrict__ hb, const int* __restrict__ gstart,
                                                const float* __restrict__ fc1w, const float* __restrict__ fc1b,
                                                const float* __restrict__ fc2w, const float* __restrict__ fc2b,
                                                float* __restrict__ out) {
    __shared__ float W1[DIM * DIM];
    __shared__ float red[4 * DIM];
    __shared__ float tbuf[DIM];
    __shared__ float obuf[CNUM];
    int tid = threadIdx.x, lane = tid & 63, wv = tid >> 6;
    int gid = blockIdx.x;

    const float4* W4 = (const float4*)fc1w;
    float4* W1s = (float4*)W1;
    #pragma unroll
    for (int i = 0; i < 4; ++i) W1s[tid + 256 * i] = W4[tid + 256 * i];

    int s = gstart[gid], e = gstart[gid + 1];
    float acc = 0.f;
    for (int i = s + wv; i < e; i += 4) acc += bfs(hb[((size_t)i << 6) + lane]);
    red[wv * DIM + lane] = acc;
    __syncthreads();

    if (wv == 0) {
        float g = red[lane] + red[DIM + lane] + red[2 * DIM + lane] + red[3 * DIM + lane];
        float t = fc1b[lane];
        #pragma unroll
        for (int k = 0; k < DIM; ++k) t += __shfl(g, k) * W1[k * DIM + lane];
        t = fmaxf(t, 0.f);
        tbuf[lane] = t;
        float o = 0.f;
        if (lane < CNUM) {
            o = fc2b[lane];
            #pragma unroll
            for (int k = 0; k < DIM; ++k) o += tbuf[k] * fc2w[k * CNUM + lane];
            obuf[lane] = o;
        }
        if (lane < CNUM) {
            float mx = obuf[0];
            #pragma unroll
            for (int k = 1; k < CNUM; ++k) mx = fmaxf(mx, obuf[k]);
            float ssum = 0.f;
            #pragma unroll
            for (int k = 0; k < CNUM; ++k) ssum += expf(obuf[k] - mx);
            out[gid * CNUM + lane] = o - mx - logf(ssum);
        }
    }
}

// ---------------- launch ----------------
static inline size_t align256(size_t x) { return (x + 255) & ~size_t(255); }

extern "C" void kernel_launch(void* const* d_in, const int* in_sizes, int n_in,
                              void* d_out, int out_size, void* d_ws, size_t ws_size,
                              hipStream_t stream) {
    const float* x     = (const float*)d_in[0];
    const int*   ei    = (const int*)d_in[1];
    const int*   batch = (const int*)d_in[2];
    const float* w1  = (const float*)d_in[3];
    const float* as1 = (const float*)d_in[4];
    const float* ad1 = (const float*)d_in[5];
    const float* b1  = (const float*)d_in[6];
    const float* w2  = (const float*)d_in[7];
    const float* as2 = (const float*)d_in[8];
    const float* ad2 = (const float*)d_in[9];
    const float* b2  = (const float*)d_in[10];
    const float* w3  = (const float*)d_in[11];
    const float* as3 = (const float*)d_in[12];
    const float* ad3 = (const float*)d_in[13];
    const float* b3  = (const float*)d_in[14];
    const float* fc1w = (const float*)d_in[15];
    const float* fc1b = (const float*)d_in[16];
    const float* fc2w = (const float*)d_in[17];
    const float* fc2b = (const float*)d_in[18];
    float* out = (float*)d_out;

    int N  = in_sizes[0] / DIM;
    int E  = in_sizes[1] / 2;
    int EP = E + N;
    int nb = (N + 255) / 256;   // scan blocks (<= 256 for N <= 65536)

    // workspace carve (fp8 h ping-pong: 16 words/row; bf16 final rows: 32)
    char* p = (char*)d_ws;
    unsigned* hbA = (unsigned*)p; p += align256(sizeof(unsigned) * (size_t)N * (DIM / 4));
    unsigned* hbB = (unsigned*)p; p += align256(sizeof(unsigned) * (size_t)N * (DIM / 4));
    unsigned* oAb = (unsigned*)p; p += align256(sizeof(unsigned) * (size_t)N * (DIM / 2));
    float* adA  = (float*)p; p += align256(sizeof(float) * (size_t)N);
    float* adB  = (float*)p; p += align256(sizeof(float) * (size_t)N);
    int*   deg  = (int*)p;   p += align256(sizeof(int) * (size_t)N);
    int*   offs = (int*)p;   p += align256(sizeof(int) * (size_t)(N + 1));
    int*   rank = (int*)p;   p += align256(sizeof(int) * (size_t)EP);
    int*   csr  = (int*)p;   p += align256(sizeof(int) * (size_t)(EP + 8));
    int*   part = (int*)p;   p += align256(sizeof(int) * (size_t)nb);
    int*   gst  = (int*)p;   p += align256(sizeof(int) * (size_t)(GNUM + 1));

    int nfb  = (N + FUS_NPB - 1) / FUS_NPB;   // fused agg+mm blocks
    int nblk = (N + AGG_NPB - 1) / AGG_NPB;   // final gat_agg blocks
    int nbt = (N + 63) / 64;                  // mm tiles
    int epBlocks = (EP + 511) / 512;          // scatter blocks

    // CSR build (dst-grouped; layer-invariant)
    hipMemsetAsync(deg, 0, sizeof(int) * (size_t)N, stream);
    deg_rank_kernel<<<(EP + 255) / 256, 256, 0, stream>>>(ei, E, N, deg, rank);
    scan_misc<<<nb + 1, 256, 0, stream>>>(deg, part, N, nb, batch, N, gst);
    scan_down<<<nb, 256, 0, stream>>>(deg, part, offs, N);

    // layer 1 mm (+ CSR scatter overlapped)
    mm_fill<<<nbt + epBlocks, 512, 0, stream>>>(x, w1, ad1, hbA, adA, N, nbt,
                                                ei, rank, E, offs, csr);
    // fused agg(1)+mm(2), agg(2)+mm(3)
    agg_mm<<<nfb, 512, 0, stream>>>(hbA, csr, adA, offs, as1, b1, w2, ad2, hbB, adB, N);
    agg_mm<<<nfb, 512, 0, stream>>>(hbB, csr, adB, offs, as2, b2, w3, ad3, hbA, adA, N);
    // final agg(3) -> bf16 rows for pooling
    gat_agg<<<nblk, 512, 0, stream>>>(hbA, csr, adA, offs, as3, b3, oAb, N);

    // fused pool + head (bf16 input)
    pool_mlp<<<GNUM, 256, 0, stream>>>((const unsigned short*)oAb, gst, fc1w, fc1b, fc2w, fc2b, out);
}

// Round 10
// 245.543 us; speedup vs baseline: 1.1022x; 1.1022x over previous
//
#include <hip/hip_runtime.h>
#include <hip/hip_bf16.h>
#include <math.h>

#define DIM 64
#define GNUM 256
#define CNUM 10

// bf16x2 pack (RNE) — final layer's streamed output only.
__device__ __forceinline__ unsigned bfpack(float a, float b) {
    unsigned ua = __builtin_bit_cast(unsigned, a);
    unsigned ub = __builtin_bit_cast(unsigned, b);
    ua += 0x7fffu + ((ua >> 16) & 1u);
    ub += 0x7fffu + ((ub >> 16) & 1u);
    return (ua >> 16) | (ub & 0xffff0000u);
}
__device__ __forceinline__ float bfs(unsigned short u) { return __builtin_bit_cast(float, (unsigned)u << 16); }

// ---------------- fp8 (OCP e4m3) pack/unpack via gfx950 HW cvt ----------------
// h rows fp8 -> 64B/row, hb = 3.2MB. R18: src-only CSR (4B/edge) halves the
// L2 stream so each XCD's private hb copy stays resident (R14 counters showed
// 5x HBM re-fetch of hb: random srcs force a copy per XCD; the csr_sd +
// write streams were evicting it).
typedef float floatx2 __attribute__((ext_vector_type(2)));
__device__ __forceinline__ unsigned fp8x4_enc(float a, float b, float c, float d) {
    int w = __builtin_amdgcn_cvt_pk_fp8_f32(a, b, 0, false);    // bytes 0,1 (RNE, sat)
    w = __builtin_amdgcn_cvt_pk_fp8_f32(c, d, w, true);         // bytes 2,3
    return (unsigned)w;
}
__device__ __forceinline__ void fp8dec8(uint2 h, float* f) {
    floatx2 p0 = __builtin_amdgcn_cvt_pk_f32_fp8((int)h.x, false);
    floatx2 p1 = __builtin_amdgcn_cvt_pk_f32_fp8((int)h.x, true);
    floatx2 p2 = __builtin_amdgcn_cvt_pk_f32_fp8((int)h.y, false);
    floatx2 p3 = __builtin_amdgcn_cvt_pk_f32_fp8((int)h.y, true);
    f[0] = p0[0]; f[1] = p0[1]; f[2] = p1[0]; f[3] = p1[1];
    f[4] = p2[0]; f[5] = p2[1]; f[6] = p3[0]; f[7] = p3[1];
}

// ---------------- CSR build ----------------
__global__ void deg_rank_kernel(const int* __restrict__ ei, int E, int N,
                                int* __restrict__ deg, int* __restrict__ rank) {
    int i = blockIdx.x * blockDim.x + threadIdx.x;
    int EP = E + N;
    if (i >= EP) return;
    int d = (i < E) ? ei[E + i] : (i - E);   // row 1 of edge_index = dst; self loops appended
    rank[i] = atomicAdd(&deg[d], 1);
}

// scan_blocks + graph_bounds, role-split by blockIdx.
__global__ __launch_bounds__(256) void scan_misc(const int* __restrict__ deg, int* __restrict__ part, int n, int nb,
                                                 const int* __restrict__ batch, int N,
                                                 int* __restrict__ gstart) {
    int bid = blockIdx.x;
    if (bid < nb) {
        __shared__ int ws[4];
        int i = bid * 256 + threadIdx.x;
        int v = (i < n) ? deg[i] : 0;
        #pragma unroll
        for (int d = 32; d >= 1; d >>= 1) v += __shfl_xor(v, d);
        if ((threadIdx.x & 63) == 0) ws[threadIdx.x >> 6] = v;
        __syncthreads();
        if (threadIdx.x == 0) part[bid] = ws[0] + ws[1] + ws[2] + ws[3];
    } else {
        for (int g = threadIdx.x; g <= GNUM; g += 256) {
            int lo = 0, hi = N;
            while (lo < hi) { int mid = (lo + hi) >> 1; if (batch[mid] < g) lo = mid + 1; else hi = mid; }
            gstart[g] = lo;
        }
    }
}

// scan_down with the top-level scan fused (nb <= 256 for N <= 65536).
__global__ __launch_bounds__(256) void scan_down(const int* __restrict__ deg, const int* __restrict__ part,
                                                 int* __restrict__ offs, int n) {
    __shared__ int ws[4];
    __shared__ int base_s;
    int tid = threadIdx.x, lane = tid & 63, wid = tid >> 6;
    int pv = (tid < (int)blockIdx.x) ? part[tid] : 0;
    #pragma unroll
    for (int d = 32; d >= 1; d >>= 1) pv += __shfl_xor(pv, d);
    if (lane == 0) ws[wid] = pv;
    __syncthreads();
    if (tid == 0) base_s = ws[0] + ws[1] + ws[2] + ws[3];
    __syncthreads();
    int i = blockIdx.x * 256 + tid;
    int v = (i < n) ? deg[i] : 0;
    int x = v;
    #pragma unroll
    for (int d = 1; d < 64; d <<= 1) { int t = __shfl_up(x, d); if (lane >= d) x += t; }
    if (lane == 63) ws[wid] = x;
    __syncthreads();
    int add = base_s;
    for (int w = 0; w < wid; ++w) add += ws[w];
    if (i < n) offs[i] = add + x - v;
    if (i == n - 1) offs[n] = add + x;
}

// ---------------- 4-wide fp8 gather (R16 proven loop) ----------------
// 8-lane group per node; lane fg reads uint2 (8 fp8) at row*64B + fg*8B ->
// one coalesced 64B transaction per edge. HW cvt decode.
__device__ __forceinline__ void gat_gather4(const unsigned* __restrict__ hb,
                                            const int2* __restrict__ lsw,
                                            int ls, int deg, int fg,
                                            float& a0, float& a1, float& a2, float& a3,
                                            float& a4, float& a5, float& a6, float& a7,
                                            float& sw) {
    for (int eb = 0; eb < deg; eb += 4) {
        int t = ls + eb;
        int2 eA = lsw[t], eB = lsw[t + 1], eC = lsw[t + 2], eD = lsw[t + 3];
        float wA = __builtin_bit_cast(float, eA.y);
        float wB = (eb + 1 < deg) ? __builtin_bit_cast(float, eB.y) : 0.f;
        float wC = (eb + 2 < deg) ? __builtin_bit_cast(float, eC.y) : 0.f;
        float wD = (eb + 3 < deg) ? __builtin_bit_cast(float, eD.y) : 0.f;
        const uint2 hA = *(const uint2*)(hb + ((size_t)eA.x << 4) + (fg << 1));
        const uint2 hB = *(const uint2*)(hb + ((size_t)eB.x << 4) + (fg << 1));
        const uint2 hC = *(const uint2*)(hb + ((size_t)eC.x << 4) + (fg << 1));
        const uint2 hD = *(const uint2*)(hb + ((size_t)eD.x << 4) + (fg << 1));
        float fA[8], fB[8], fC[8], fD[8];
        fp8dec8(hA, fA); fp8dec8(hB, fB); fp8dec8(hC, fC); fp8dec8(hD, fD);
        sw += wA + wB + wC + wD;
        a0 += wA * fA[0] + wB * fB[0] + wC * fC[0] + wD * fD[0];
        a1 += wA * fA[1] + wB * fB[1] + wC * fC[1] + wD * fD[1];
        a2 += wA * fA[2] + wB * fB[2] + wC * fC[2] + wD * fD[2];
        a3 += wA * fA[3] + wB * fB[3] + wC * fC[3] + wD * fD[3];
        a4 += wA * fA[4] + wB * fB[4] + wC * fC[4] + wD * fD[4];
        a5 += wA * fA[5] + wB * fB[5] + wC * fC[5] + wD * fD[5];
        a6 += wA * fA[6] + wB * fB[6] + wC * fC[6] + wD * fD[6];
        a7 += wA * fA[7] + wB * fB[7] + wC * fC[7] + wD * fD[7];
    }
}

// dst of block-local edge i: largest li in [0,63] with soffs[li]-estart <= i.
// 6-step binary search over LDS soffs (broadcast reads).
__device__ __forceinline__ int edge_dst(const int* __restrict__ soffs, int estart, int i) {
    int lo = 0, hi = 63;
    #pragma unroll
    for (int s = 0; s < 6; ++s) {
        int mid = (lo + hi + 1) >> 1;
        if (soffs[mid] - estart <= i) lo = mid; else hi = mid - 1;
    }
    return lo;
}

// ---------------- 512-thread 64x64 mm pieces ----------------
#define XSTR 68
// hbn rows fp8 (16 words / 64B). Epilogue computes as (src dot) + ad (dst dot).
__device__ __forceinline__ void mm_core_512(const float* __restrict__ xT, const float* __restrict__ Ws,
                                            const float* __restrict__ a_s, const float* __restrict__ a_d,
                                            unsigned* __restrict__ hbn, float* __restrict__ asn,
                                            float* __restrict__ adn, int base, int N) {
    int tid = threadIdx.x;
    int tx = tid & 15, ty = tid >> 4;          // ty 0..31
    int c0 = tx << 2, r0 = ty << 1;
    float acc[2][4] = {{0.f}};
    #pragma unroll 8
    for (int k = 0; k < DIM; ++k) {
        float2 xv = *(const float2*)(xT + k * XSTR + r0);
        float4 wv = *(const float4*)(Ws + k * DIM + c0);
        acc[0][0] += xv.x * wv.x; acc[0][1] += xv.x * wv.y; acc[0][2] += xv.x * wv.z; acc[0][3] += xv.x * wv.w;
        acc[1][0] += xv.y * wv.x; acc[1][1] += xv.y * wv.y; acc[1][2] += xv.y * wv.z; acc[1][3] += xv.y * wv.w;
    }
    float4 av = *(const float4*)(a_s + c0);
    float4 dv = *(const float4*)(a_d + c0);
    #pragma unroll
    for (int ri = 0; ri < 2; ++ri) {
        int grow = base + r0 + ri;
        float s1 = acc[ri][0] * av.x + acc[ri][1] * av.y + acc[ri][2] * av.z + acc[ri][3] * av.w;
        float s2 = acc[ri][0] * dv.x + acc[ri][1] * dv.y + acc[ri][2] * dv.z + acc[ri][3] * dv.w;
        #pragma unroll
        for (int d = 1; d <= 8; d <<= 1) { s1 += __shfl_xor(s1, d); s2 += __shfl_xor(s2, d); }
        if (grow < N) {
            hbn[((size_t)grow << 4) + tx] = fp8x4_enc(acc[ri][0], acc[ri][1], acc[ri][2], acc[ri][3]);
            if (tx == 0) { asn[grow] = s1; adn[grow] = s2; }
        }
    }
}

// layer-1 mm (f32 input, 512 threads) + atomic-free CSR scatter (src-only, 4B/edge).
__global__ __launch_bounds__(512) void mm_fill(const float* __restrict__ in, const float* __restrict__ W,
                                               const float* __restrict__ a_s, const float* __restrict__ a_d,
                                               unsigned* __restrict__ hb, float* __restrict__ as_,
                                               float* __restrict__ ad_, int N, int nbt,
                                               const int* __restrict__ ei, const int* __restrict__ rank, int E,
                                               const int* __restrict__ offs, int* __restrict__ csr) {
    int bid = blockIdx.x;
    if (bid < nbt) {
        __shared__ float Ws[DIM * DIM];
        __shared__ float xT[XSTR * DIM];
        int tid = threadIdx.x;
        int base = bid * 64;

        const float4* W4 = (const float4*)W;
        float4* Ws4 = (float4*)Ws;
        Ws4[tid] = W4[tid];
        Ws4[tid + 512] = W4[tid + 512];

        {
            int row = tid >> 3;
            int kb = (tid & 7) << 3;
            int grow = base + row;
            int crow = grow < N ? grow : N - 1;
            const float4* xr = (const float4*)(in + ((size_t)crow << 6) + kb);
            float4 v0 = xr[0], v1 = xr[1];
            xT[(kb + 0) * XSTR + row] = v0.x;  xT[(kb + 1) * XSTR + row] = v0.y;
            xT[(kb + 2) * XSTR + row] = v0.z;  xT[(kb + 3) * XSTR + row] = v0.w;
            xT[(kb + 4) * XSTR + row] = v1.x;  xT[(kb + 5) * XSTR + row] = v1.y;
            xT[(kb + 6) * XSTR + row] = v1.z;  xT[(kb + 7) * XSTR + row] = v1.w;
        }
        __syncthreads();
        mm_core_512(xT, Ws, a_s, a_d, hb, as_, ad_, base, N);
    } else {
        int i = (bid - nbt) * 512 + threadIdx.x;
        int EP = E + N;
        if (i >= EP) return;
        int s, d;
        if (i < E) { s = ei[i]; d = ei[E + i]; } else { s = i - E; d = i - E; }
        csr[offs[d] + rank[i]] = s;
    }
}

// ---------------- fused agg(layer k) + mm(layer k+1), 512 threads ----------------
#define FUS_NPB 64
#define FUS_CAP 2560
__global__ __launch_bounds__(512) void agg_mm(const unsigned* __restrict__ hbp,
                                              const int* __restrict__ csr,
                                              const float* __restrict__ asp,
                                              const float* __restrict__ adp,
                                              const int* __restrict__ offs,
                                              const float* __restrict__ bias,
                                              const float* __restrict__ W,
                                              const float* __restrict__ a_s,
                                              const float* __restrict__ a_d,
                                              unsigned* __restrict__ hbn,
                                              float* __restrict__ asn,
                                              float* __restrict__ adn, int N) {
    __shared__ int soffs[FUS_NPB + 1];
    __shared__ float adl[FUS_NPB];
    __shared__ int2 lsw[FUS_CAP + 4];          // 20 KB; reused as Ws (16 KB) in mm phase
    __shared__ float xT[XSTR * DIM];           // 17.4 KB
    float* Ws = (float*)lsw;

    int tid = threadIdx.x;
    int base = blockIdx.x * FUS_NPB;
    if (tid <= FUS_NPB) {
        int n = base + tid;
        soffs[tid] = offs[n < N ? n : N];
    }
    if (tid < FUS_NPB) {
        int n = base + tid;
        adl[tid] = (n < N) ? adp[n] : 0.f;
    }
    __syncthreads();
    int estart = soffs[0];
    int nE = soffs[FUS_NPB] - estart;
    bool inLds = (nE <= FUS_CAP);
    if (inLds) {
        for (int i = tid; i < nE; i += 512) {
            int s = csr[estart + i];
            int dli = edge_dst(soffs, estart, i);
            float e = asp[s] + adl[dli];
            e = (e > 0.f) ? e : 0.2f * e;
            lsw[i] = make_int2(s, __builtin_bit_cast(int, expf(e)));
        }
        if (tid < 4) lsw[nE + tid] = make_int2(0, 0);
    }
    __syncthreads();

    int li = tid >> 3, fg = tid & 7;           // one 8-lane group per node
    int node = base + li;
    int ls = soffs[li] - estart;
    int deg = soffs[li + 1] - soffs[li];

    float a0 = 0.f, a1 = 0.f, a2 = 0.f, a3 = 0.f;
    float a4 = 0.f, a5 = 0.f, a6 = 0.f, a7 = 0.f, sw = 0.f;
    if (inLds) {
        gat_gather4(hbp, lsw, ls, deg, fg, a0, a1, a2, a3, a4, a5, a6, a7, sw);
    } else {
        // cold fallback: same math from global (src-only csr), clamped/masked
        float adi = adl[li];
        for (int eb = 0; eb < deg; eb += 4) {
            int t = estart + ls + eb;
            float wv[4]; int sv[4];
            #pragma unroll
            for (int k = 0; k < 4; ++k) {
                int s = (eb + k < deg) ? csr[t + k] : 0;
                s = s < 0 ? 0 : (s >= N ? N - 1 : s);
                float e = asp[s] + adi;
                e = (e > 0.f) ? e : 0.2f * e;
                wv[k] = (eb + k < deg) ? expf(e) : 0.f;
                sv[k] = s;
            }
            #pragma unroll
            for (int k = 0; k < 4; ++k) {
                const uint2 hv = *(const uint2*)(hbp + ((size_t)sv[k] << 4) + (fg << 1));
                float fv[8];
                fp8dec8(hv, fv);
                sw += wv[k];
                a0 += wv[k] * fv[0]; a1 += wv[k] * fv[1];
                a2 += wv[k] * fv[2]; a3 += wv[k] * fv[3];
                a4 += wv[k] * fv[4]; a5 += wv[k] * fv[5];
                a6 += wv[k] * fv[6]; a7 += wv[k] * fv[7];
            }
        }
    }

    float inv = 1.f / (sw + 1e-16f);
    const float4 b0 = *(const float4*)(bias + (fg << 3));
    const float4 b1 = *(const float4*)(bias + (fg << 3) + 4);
    float o0 = a0 * inv + b0.x, o1 = a1 * inv + b0.y, o2 = a2 * inv + b0.z, o3 = a3 * inv + b0.w;
    float o4 = a4 * inv + b1.x, o5 = a5 * inv + b1.y, o6 = a6 * inv + b1.z, o7 = a7 * inv + b1.w;
    float n2 = o0 * o0 + o1 * o1 + o2 * o2 + o3 * o3 + o4 * o4 + o5 * o5 + o6 * o6 + o7 * o7;
    #pragma unroll
    for (int d = 1; d <= 4; d <<= 1) n2 += __shfl_xor(n2, d);   // across the 8 fg lanes
    float innrm = 1.f / fmaxf(sqrtf(n2), 1e-12f);
    if (node >= N) innrm = 0.f;                // keep xT clean for pad rows
    int kb = fg << 3;
    xT[(kb + 0) * XSTR + li] = fmaxf(o0 * innrm, 0.f);
    xT[(kb + 1) * XSTR + li] = fmaxf(o1 * innrm, 0.f);
    xT[(kb + 2) * XSTR + li] = fmaxf(o2 * innrm, 0.f);
    xT[(kb + 3) * XSTR + li] = fmaxf(o3 * innrm, 0.f);
    xT[(kb + 4) * XSTR + li] = fmaxf(o4 * innrm, 0.f);
    xT[(kb + 5) * XSTR + li] = fmaxf(o5 * innrm, 0.f);
    xT[(kb + 6) * XSTR + li] = fmaxf(o6 * innrm, 0.f);
    xT[(kb + 7) * XSTR + li] = fmaxf(o7 * innrm, 0.f);
    __syncthreads();                            // agg done; lsw region free

    const float4* W4 = (const float4*)W;
    float4* Ws4 = (float4*)Ws;
    Ws4[tid] = W4[tid];
    Ws4[tid + 512] = W4[tid + 512];
    __syncthreads();
    mm_core_512(xT, Ws, a_s, a_d, hbn, asn, adn, base, N);
}

// ---------------- per-node softmax-aggregate (final layer, 512 threads) ----------------
// Reads fp8 hb, writes bf16 rows (streamed, pool accuracy) to outb.
#define AGG_NPB 64
#define AGG_CAP 2560
__global__ __launch_bounds__(512) void gat_agg(const unsigned* __restrict__ hb,
                                               const int* __restrict__ csr,
                                               const float* __restrict__ as_,
                                               const float* __restrict__ ad_,
                                               const int* __restrict__ offs,
                                               const float* __restrict__ bias,
                                               unsigned* __restrict__ outb, int N) {
    __shared__ int soffs[AGG_NPB + 1];
    __shared__ float adl[AGG_NPB];
    __shared__ int2 lsw[AGG_CAP + 4];
    int tid = threadIdx.x;
    int base = blockIdx.x * AGG_NPB;
    if (tid <= AGG_NPB) {
        int n = base + tid;
        soffs[tid] = offs[n < N ? n : N];
    }
    if (tid < AGG_NPB) {
        int n = base + tid;
        adl[tid] = (n < N) ? ad_[n] : 0.f;
    }
    __syncthreads();
    int estart = soffs[0];
    int nE = soffs[AGG_NPB] - estart;
    bool inLds = (nE <= AGG_CAP);
    if (inLds) {
        for (int i = tid; i < nE; i += 512) {
            int s = csr[estart + i];
            int dli = edge_dst(soffs, estart, i);
            float e = as_[s] + adl[dli];
            e = (e > 0.f) ? e : 0.2f * e;
            lsw[i] = make_int2(s, __builtin_bit_cast(int, expf(e)));
        }
        if (tid < 4) lsw[nE + tid] = make_int2(0, 0);
    }
    __syncthreads();

    int li = tid >> 3, fg = tid & 7;
    int node = base + li;
    int ls = soffs[li] - estart;
    int deg = soffs[li + 1] - soffs[li];

    float a0 = 0.f, a1 = 0.f, a2 = 0.f, a3 = 0.f;
    float a4 = 0.f, a5 = 0.f, a6 = 0.f, a7 = 0.f, sw = 0.f;
    if (inLds) {
        gat_gather4(hb, lsw, ls, deg, fg, a0, a1, a2, a3, a4, a5, a6, a7, sw);
    } else {
        float adi = (node < N) ? ad_[node] : 0.f;
        for (int eb = 0; eb < deg; eb += 4) {
            int t = estart + ls + eb;
            float wv[4]; int sv[4];
            #pragma unroll
            for (int k = 0; k < 4; ++k) {
                int s = (eb + k < deg) ? csr[t + k] : 0;
                s = s < 0 ? 0 : (s >= N ? N - 1 : s);
                float e = as_[s] + adi;
                e = (e > 0.f) ? e : 0.2f * e;
                wv[k] = (eb + k < deg) ? expf(e) : 0.f;
                sv[k] = s;
            }
            #pragma unroll
            for (int k = 0; k < 4; ++k) {
                const uint2 hv = *(const uint2*)(hb + ((size_t)sv[k] << 4) + (fg << 1));
                float fv[8];
                fp8dec8(hv, fv);
                sw += wv[k];
                a0 += wv[k] * fv[0]; a1 += wv[k] * fv[1];
                a2 += wv[k] * fv[2]; a3 += wv[k] * fv[3];
                a4 += wv[k] * fv[4]; a5 += wv[k] * fv[5];
                a6 += wv[k] * fv[6]; a7 += wv[k] * fv[7];
            }
        }
    }

    float inv = 1.f / (sw + 1e-16f);
    const float4 b0 = *(const float4*)(bias + (fg << 3));
    const float4 b1 = *(const float4*)(bias + (fg << 3) + 4);
    float o0 = a0 * inv + b0.x, o1 = a1 * inv + b0.y, o2 = a2 * inv + b0.z, o3 = a3 * inv + b0.w;
    float o4 = a4 * inv + b1.x, o5 = a5 * inv + b1.y, o6 = a6 * inv + b1.z, o7 = a7 * inv + b1.w;
    float n2 = o0 * o0 + o1 * o1 + o2 * o2 + o3 * o3 + o4 * o4 + o5 * o5 + o6 * o6 + o7 * o7;
    #pragma unroll
    for (int d = 1; d <= 4; d <<= 1) n2 += __shfl_xor(n2, d);   // across the 8 fg lanes
    float innrm = 1.f / fmaxf(sqrtf(n2), 1e-12f);
    if (node < N) {
        uint4 o;
        o.x = bfpack(fmaxf(o0 * innrm, 0.f), fmaxf(o1 * innrm, 0.f));
        o.y = bfpack(fmaxf(o2 * innrm, 0.f), fmaxf(o3 * innrm, 0.f));
        o.z = bfpack(fmaxf(o4 * innrm, 0.f), fmaxf(o5 * innrm, 0.f));
        o.w = bfpack(fmaxf(o6 * innrm, 0.f), fmaxf(o7 * innrm, 0.f));
        *(uint4*)(outb + ((size_t)node << 5) + (fg << 2)) = o;
    }
}

// ---------------- fused global_add_pool + MLP + log_softmax ----------------
__global__ __launch_bounds__(256) void pool_mlp(const unsigned short* __restrict__ hb, const int* __restrict__ gstart,
                                                const float* __restrict__ fc1w, const float* __restrict__ fc1b,
                                                const float* __restrict__ fc2w, const float* __restrict__ fc2b,
                                                float* __restrict__ out) {
    __shared__ float W1[DIM * DIM];
    __shared__ float red[4 * DIM];
    __shared__ float tbuf[DIM];
    __shared__ float obuf[CNUM];
    int tid = threadIdx.x, lane = tid & 63, wv = tid >> 6;
    int gid = blockIdx.x;

    const float4* W4 = (const float4*)fc1w;
    float4* W1s = (float4*)W1;
    #pragma unroll
    for (int i = 0; i < 4; ++i) W1s[tid + 256 * i] = W4[tid + 256 * i];

    int s = gstart[gid], e = gstart[gid + 1];
    float acc = 0.f;
    for (int i = s + wv; i < e; i += 4) acc += bfs(hb[((size_t)i << 6) + lane]);
    red[wv * DIM + lane] = acc;
    __syncthreads();

    if (wv == 0) {
        float g = red[lane] + red[DIM + lane] + red[2 * DIM + lane] + red[3 * DIM + lane];
        float t = fc1b[lane];
        #pragma unroll
        for (int k = 0; k < DIM; ++k) t += __shfl(g, k) * W1[k * DIM + lane];
        t = fmaxf(t, 0.f);
        tbuf[lane] = t;
        float o = 0.f;
        if (lane < CNUM) {
            o = fc2b[lane];
            #pragma unroll
            for (int k = 0; k < DIM; ++k) o += tbuf[k] * fc2w[k * CNUM + lane];
            obuf[lane] = o;
        }
        if (lane < CNUM) {
            float mx = obuf[0];
            #pragma unroll
            for (int k = 1; k < CNUM; ++k) mx = fmaxf(mx, obuf[k]);
            float ssum = 0.f;
            #pragma unroll
            for (int k = 0; k < CNUM; ++k) ssum += expf(obuf[k] - mx);
            out[gid * CNUM + lane] = o - mx - logf(ssum);
        }
    }
}

// ---------------- launch ----------------
static inline size_t align256(size_t x) { return (x + 255) & ~size_t(255); }

extern "C" void kernel_launch(void* const* d_in, const int* in_sizes, int n_in,
                              void* d_out, int out_size, void* d_ws, size_t ws_size,
                              hipStream_t stream) {
    const float* x     = (const float*)d_in[0];
    const int*   ei    = (const int*)d_in[1];
    const int*   batch = (const int*)d_in[2];
    const float* w1  = (const float*)d_in[3];
    const float* as1 = (const float*)d_in[4];
    const float* ad1 = (const float*)d_in[5];
    const float* b1  = (const float*)d_in[6];
    const float* w2  = (const float*)d_in[7];
    const float* as2 = (const float*)d_in[8];
    const float* ad2 = (const float*)d_in[9];
    const float* b2  = (const float*)d_in[10];
    const float* w3  = (const float*)d_in[11];
    const float* as3 = (const float*)d_in[12];
    const float* ad3 = (const float*)d_in[13];
    const float* b3  = (const float*)d_in[14];
    const float* fc1w = (const float*)d_in[15];
    const float* fc1b = (const float*)d_in[16];
    const float* fc2w = (const float*)d_in[17];
    const float* fc2b = (const float*)d_in[18];
    float* out = (float*)d_out;

    int N  = in_sizes[0] / DIM;
    int E  = in_sizes[1] / 2;
    int EP = E + N;
    int nb = (N + 255) / 256;   // scan blocks (<= 256 for N <= 65536)

    // workspace carve (fp8 h ping-pong: 16 words/row; bf16 final rows: 32 words)
    char* p = (char*)d_ws;
    unsigned* hbA = (unsigned*)p; p += align256(sizeof(unsigned) * (size_t)N * (DIM / 4));
    unsigned* hbB = (unsigned*)p; p += align256(sizeof(unsigned) * (size_t)N * (DIM / 4));
    unsigned* oAb = (unsigned*)p; p += align256(sizeof(unsigned) * (size_t)N * (DIM / 2));
    float* asA  = (float*)p; p += align256(sizeof(float) * (size_t)N);
    float* adA  = (float*)p; p += align256(sizeof(float) * (size_t)N);
    float* asB  = (float*)p; p += align256(sizeof(float) * (size_t)N);
    float* adB  = (float*)p; p += align256(sizeof(float) * (size_t)N);
    int*   deg  = (int*)p;   p += align256(sizeof(int) * (size_t)N);
    int*   offs = (int*)p;   p += align256(sizeof(int) * (size_t)(N + 1));
    int*   rank = (int*)p;   p += align256(sizeof(int) * (size_t)EP);
    int*   csr  = (int*)p;   p += align256(sizeof(int) * (size_t)(EP + 8));
    int*   part = (int*)p;   p += align256(sizeof(int) * (size_t)nb);
    int*   gst  = (int*)p;   p += align256(sizeof(int) * (size_t)(GNUM + 1));

    int nfb  = (N + FUS_NPB - 1) / FUS_NPB;   // fused agg+mm blocks
    int nblk = (N + AGG_NPB - 1) / AGG_NPB;   // final gat_agg blocks
    int nbt = (N + 63) / 64;                  // mm tiles
    int epBlocks = (EP + 511) / 512;          // scatter blocks

    // CSR build (dst-grouped; layer-invariant)
    hipMemsetAsync(deg, 0, sizeof(int) * (size_t)N, stream);
    deg_rank_kernel<<<(EP + 255) / 256, 256, 0, stream>>>(ei, E, N, deg, rank);
    scan_misc<<<nb + 1, 256, 0, stream>>>(deg, part, N, nb, batch, N, gst);
    scan_down<<<nb, 256, 0, stream>>>(deg, part, offs, N);

    // layer 1 mm (+ CSR scatter overlapped)
    mm_fill<<<nbt + epBlocks, 512, 0, stream>>>(x, w1, as1, ad1, hbA, asA, adA, N, nbt,
                                                ei, rank, E, offs, csr);
    // fused agg(1)+mm(2), agg(2)+mm(3)
    agg_mm<<<nfb, 512, 0, stream>>>(hbA, csr, asA, adA, offs, b1, w2, as2, ad2,
                                    hbB, asB, adB, N);
    agg_mm<<<nfb, 512, 0, stream>>>(hbB, csr, asB, adB, offs, b2, w3, as3, ad3,
                                    hbA, asA, adA, N);
    // final agg(3) -> bf16 rows for pooling
    gat_agg<<<nblk, 512, 0, stream>>>(hbA, csr, asA, adA, offs, b3, oAb, N);

    // fused pool + head (bf16 input)
    pool_mlp<<<GNUM, 256, 0, stream>>>((const unsigned short*)oAb, gst, fc1w, fc1b, fc2w, fc2b, out);
}